// Round 11
// baseline (468.563 us; speedup 1.0000x reference)
//
#include <hip/hip_runtime.h>
#include <hip/hip_cooperative_groups.h>
#include <float.h>

// ROI max-pool via sliding-4-max pyramid, single cooperative kernel.
//   S4x[y][x]  = max fm[y][x..x+3]   (indices clamped at edge)
//   S4y[y][x]  = max fm[y..y+3][x]
//   S4xy[y][x] = max fm[y..y+3][x..x+3]
// Phase 1 (build) and phase 2 (query) separated by grid.sync() instead of a
// kernel boundary. blockIdx%8 keeps (batch, y-quartile / i-group) pinned to
// one XCD so each XCD's table slice stays in its 4 MiB L2 across phases.
// Query: bin range (len<=15) covered by <=4 overlapping spans/dim.
// Reference semantics:
//   h0=(int)(H*r0); h1=(int)(H*r2); step=(h1-h0)/7
//   bin i<6: [h0+i*step, h0+(i+1)*step); bin 6: [h0+6*step, h1)
//   step==0 -> all valid pixels in bin 6; empty bin -> -FLT_MAX
constexpr int H = 64, W = 64, C = 256, PH = 7, PW = 7;

namespace cg = cooperative_groups;

typedef float f32x4 __attribute__((ext_vector_type(4)));

__device__ __forceinline__ f32x4 vmax4(f32x4 a, f32x4 b) {
    f32x4 r;
    r.x = fmaxf(a.x, b.x); r.y = fmaxf(a.y, b.y);
    r.z = fmaxf(a.z, b.z); r.w = fmaxf(a.w, b.w);
    return r;
}

// ---------- shared device bodies ----------
__device__ __forceinline__ void build_body(
    int bx, int lane, int wave,
    const float* __restrict__ fm, float* __restrict__ s4x,
    float* __restrict__ s4y, float* __restrict__ s4xy,
    f32x4 (*lds_fm)[64], f32x4 (*lds_sx)[64])
{
    const int x8 = bx & 7;
    const int z  = bx >> 3;                          // 0..255
    const int b  = x8 >> 2;                          // batch
    const int quart = x8 & 3;                        // y-quartile (XCD match)
    const int x  = z & (W - 1);
    const int y0 = quart * 16 + ((z >> 6) << 2);     // 4-row band

    const int x1 = min(x + 1, W - 1), x2 = min(x + 2, W - 1), x3 = min(x + 3, W - 1);
    const float* fmb = fm + (size_t)b * H * W * C + (size_t)lane * 4;

    #pragma unroll
    for (int s = 0; s < 2; ++s) {
        const int slot = wave + 4 * s;
        if (slot < 7) {
            const int y = min(y0 + slot, H - 1);     // clamp == table edge rule
            const float* row = fmb + (size_t)y * W * C;
            f32x4 v0 = *(const f32x4*)(row + (size_t)x  * C);
            f32x4 v1 = *(const f32x4*)(row + (size_t)x1 * C);
            f32x4 v2 = *(const f32x4*)(row + (size_t)x2 * C);
            f32x4 v3 = *(const f32x4*)(row + (size_t)x3 * C);
            lds_fm[slot][lane] = v0;
            lds_sx[slot][lane] = vmax4(vmax4(v0, v1), vmax4(v2, v3));
        }
    }
    __syncthreads();

    const int y = y0 + wave;
    const f32x4 sx = lds_sx[wave][lane];
    const f32x4 sy = vmax4(vmax4(lds_fm[wave][lane],     lds_fm[wave + 1][lane]),
                           vmax4(lds_fm[wave + 2][lane], lds_fm[wave + 3][lane]));
    const f32x4 sxy = vmax4(vmax4(lds_sx[wave][lane],     lds_sx[wave + 1][lane]),
                            vmax4(lds_sx[wave + 2][lane], lds_sx[wave + 3][lane]));

    const size_t o = ((size_t)(b * H + y) * W + x) * C + (size_t)lane * 4;
    *(f32x4*)(s4x  + o) = sx;
    *(f32x4*)(s4y  + o) = sy;
    *(f32x4*)(s4xy + o) = sxy;
}

__device__ __forceinline__ void query_unit(
    int x8, int n, int lane, int wave,
    const float* __restrict__ fm, const float* __restrict__ rois,
    const float* __restrict__ s4x, const float* __restrict__ s4y,
    const float* __restrict__ s4xy, float* __restrict__ out, int R)
{
    const int b = x8 >> 2;                           // batch
    const int g = x8 & 3;                            // i-group

    int i, id;
    if (g < 3) {
        i  = 2 * g + (n & 1);
        id = (n >> 1) * 4 + wave;                    // [0, 1792)
    } else {
        if (n >= 448) return;                        // pad: idle
        i  = 6;
        id = n * 4 + wave;
    }
    const int r = id / 7;                            // roi
    const int j = id - 7 * r;                        // col bin

    const float* roi = rois + ((size_t)b * R + r) * 4;
    int h0 = (int)((float)H * roi[0]);               // trunc == astype(int32)
    int w0 = (int)((float)W * roi[1]);
    int h1 = (int)((float)H * roi[2]);
    int w1 = (int)((float)W * roi[3]);
    int hs = (h1 - h0) / PH;
    int ws = (w1 - w0) / PW;

    int ys, ye, xs, xe;
    if (hs > 0) { ys = h0 + i * hs; ye = (i < PH - 1) ? (ys + hs) : h1; }
    else        { ys = h0;          ye = (i == PH - 1) ? h1 : h0; }
    if (ws > 0) { xs = w0 + j * ws; xe = (j < PW - 1) ? (xs + ws) : w1; }
    else        { xs = w0;          xe = (j == PW - 1) ? w1 : w0; }
    ys = __builtin_amdgcn_readfirstlane(max(ys, 0));
    ye = __builtin_amdgcn_readfirstlane(min(ye, H));
    xs = __builtin_amdgcn_readfirstlane(max(xs, 0));
    xe = __builtin_amdgcn_readfirstlane(min(xe, W));

    const int hl = ye - ys, wl = xe - xs;
    const f32x4 NEG = {-FLT_MAX, -FLT_MAX, -FLT_MAX, -FLT_MAX};
    f32x4 a0 = NEG, a1 = NEG, a2 = NEG, a3 = NEG;

    if (hl > 0 && wl > 0) {
        const bool y4 = hl >= 4, x4 = wl >= 4;       // len<=15 -> <=4 spans/dim
        const int ny = y4 ? (hl + 3) >> 2 : hl;
        const int nx = x4 ? (wl + 3) >> 2 : wl;
        const int ystep = y4 ? 4 : 1, xstep = x4 ? 4 : 1;
        const int ycl = y4 ? ye - 4 : ye - 1;
        const int xcl = x4 ? xe - 4 : xe - 1;
        const float* tb = y4 ? (x4 ? s4xy : s4y) : (x4 ? s4x : fm);
        const float* tbb = tb + (size_t)b * H * W * C + lane * 4;

        const int xo0 = min(xs,             xcl) * C;
        const int xo1 = min(xs + xstep,     xcl) * C;
        const int xo2 = min(xs + 2 * xstep, xcl) * C;
        const int xo3 = min(xs + 3 * xstep, xcl) * C;

        #pragma unroll
        for (int ky = 0; ky < 4; ++ky) {
            if (ky < ny) {                           // wave-uniform guard
                const int y = min(ys + ystep * ky, ycl);
                const float* rowp = tbb + (size_t)y * (W * C);
                a0 = vmax4(a0, *(const f32x4*)(rowp + xo0));
                if (nx > 1) a1 = vmax4(a1, *(const f32x4*)(rowp + xo1));
                if (nx > 2) a2 = vmax4(a2, *(const f32x4*)(rowp + xo2));
                if (nx > 3) a3 = vmax4(a3, *(const f32x4*)(rowp + xo3));
            }
        }
    }
    const f32x4 acc = vmax4(vmax4(a0, a1), vmax4(a2, a3));

    size_t o = ((((size_t)b * R + r) * PH + i) * PW + j) * C + (size_t)lane * 4;
    __builtin_nontemporal_store(acc, reinterpret_cast<f32x4*>(out + o));
}

// ---------- fused cooperative kernel: grid MUST be 2048 x 256 ----------
__global__ __launch_bounds__(256) void roi_pool_fused(
    const float* __restrict__ fm, const float* __restrict__ rois,
    float* __restrict__ s4x, float* __restrict__ s4y, float* __restrict__ s4xy,
    float* __restrict__ out, int R)
{
    __shared__ f32x4 lds_fm[7][64];
    __shared__ f32x4 lds_sx[7][64];

    const int lane = threadIdx.x & 63;
    const int wave = __builtin_amdgcn_readfirstlane(threadIdx.x >> 6);

    build_body(blockIdx.x, lane, wave, fm, s4x, s4y, s4xy, lds_fm, lds_sx);

    __threadfence();
    cg::this_grid().sync();

    // query: 7168 units folded onto 2048 blocks, preserving blockIdx%8 class
    const int x8   = blockIdx.x & 7;
    const int base = blockIdx.x >> 3;                // 0..255
    #pragma unroll
    for (int k = 0; k < 4; ++k) {
        const int n = base + 256 * k;                // unit within class
        if (n < 896)
            query_unit(x8, n, lane, wave, fm, rois, s4x, s4y, s4xy, out, R);
    }
}

// ---------- standalone two-kernel path (fallback) ----------
__global__ __launch_bounds__(256) void build_tables(
    const float* __restrict__ fm, float* __restrict__ s4x,
    float* __restrict__ s4y, float* __restrict__ s4xy)
{
    __shared__ f32x4 lds_fm[7][64];
    __shared__ f32x4 lds_sx[7][64];
    const int lane = threadIdx.x & 63;
    const int wave = __builtin_amdgcn_readfirstlane(threadIdx.x >> 6);
    build_body(blockIdx.x, lane, wave, fm, s4x, s4y, s4xy, lds_fm, lds_sx);
}

__global__ __launch_bounds__(256) void roi_pool_q(
    const float* __restrict__ fm, const float* __restrict__ rois,
    const float* __restrict__ s4x, const float* __restrict__ s4y,
    const float* __restrict__ s4xy, float* __restrict__ out, int R)
{
    const int lane = threadIdx.x & 63;
    const int wave = __builtin_amdgcn_readfirstlane(threadIdx.x >> 6);
    query_unit(blockIdx.x & 7, blockIdx.x >> 3, lane, wave,
               fm, rois, s4x, s4y, s4xy, out, R);
}

// ---- verified direct fallback (R5 kernel) if ws too small ----
__global__ __launch_bounds__(256) void roi_pool_direct(
    const float* __restrict__ fm, const float* __restrict__ rois,
    float* __restrict__ out, int R)
{
    const int lane = threadIdx.x & 63;
    const int wave = __builtin_amdgcn_readfirstlane(threadIdx.x >> 6);
    const int b = blockIdx.x & 1;
    int m = (blockIdx.x >> 1) * 4 + wave;
    int j = m % PW; m /= PW;
    int i = m % PH; m /= PH;
    int r = m;

    const float* roi = rois + ((size_t)b * R + r) * 4;
    int h0 = (int)((float)H * roi[0]);
    int w0 = (int)((float)W * roi[1]);
    int h1 = (int)((float)H * roi[2]);
    int w1 = (int)((float)W * roi[3]);
    int hs = (h1 - h0) / PH;
    int ws = (w1 - w0) / PW;

    int ys, ye, xs, xe;
    if (hs > 0) { ys = h0 + i * hs; ye = (i < PH - 1) ? (ys + hs) : h1; }
    else        { ys = h0;          ye = (i == PH - 1) ? h1 : h0; }
    if (ws > 0) { xs = w0 + j * ws; xe = (j < PW - 1) ? (xs + ws) : w1; }
    else        { xs = w0;          xe = (j == PW - 1) ? w1 : w0; }
    ys = __builtin_amdgcn_readfirstlane(max(ys, 0));
    ye = __builtin_amdgcn_readfirstlane(min(ye, H));
    xs = __builtin_amdgcn_readfirstlane(max(xs, 0));
    xe = __builtin_amdgcn_readfirstlane(min(xe, W));

    const f32x4 NEG = {-FLT_MAX, -FLT_MAX, -FLT_MAX, -FLT_MAX};
    f32x4 a0 = NEG, a1 = NEG, a2 = NEG, a3 = NEG;
    const float* fmb = fm + (size_t)b * (H * W * C);
    const int lo = lane * 4;

    for (int y = ys; y < ye; y += 2) {
        const int y1 = min(y + 1, ye - 1);
        const int ro0 = y  * (W * C);
        const int ro1 = y1 * (W * C);
        for (int x = xs; x < xe; x += 2) {
            const int x1 = min(x + 1, xe - 1);
            a0 = vmax4(a0, *(const f32x4*)(fmb + ro0 + x  * C + lo));
            a1 = vmax4(a1, *(const f32x4*)(fmb + ro0 + x1 * C + lo));
            a2 = vmax4(a2, *(const f32x4*)(fmb + ro1 + x  * C + lo));
            a3 = vmax4(a3, *(const f32x4*)(fmb + ro1 + x1 * C + lo));
        }
    }
    f32x4 acc = vmax4(vmax4(a0, a1), vmax4(a2, a3));
    size_t o = ((((size_t)b * R + r) * PH + i) * PW + j) * C + (size_t)lo;
    __builtin_nontemporal_store(acc, reinterpret_cast<f32x4*>(out + o));
}

extern "C" void kernel_launch(void* const* d_in, const int* in_sizes, int n_in,
                              void* d_out, int out_size, void* d_ws, size_t ws_size,
                              hipStream_t stream) {
    const float* fm   = (const float*)d_in[0];
    const float* rois = (const float*)d_in[1];
    float* out = (float*)d_out;

    const int B = in_sizes[0] / (H * W * C);        // = 2
    int R = in_sizes[1] / (B * 4);                  // = 256

    const size_t tbl = (size_t)B * H * W * C;       // floats per table
    const size_t need = 3 * tbl * sizeof(float);    // 24 MB for B=2

    if (B == 2 && R == 256 && ws_size >= need) {
        float* s4x  = (float*)d_ws;
        float* s4y  = s4x + tbl;
        float* s4xy = s4y + tbl;

        void* args[] = { (void*)&fm, (void*)&rois, (void*)&s4x, (void*)&s4y,
                         (void*)&s4xy, (void*)&out, (void*)&R };
        hipError_t e = hipLaunchCooperativeKernel(
            (const void*)roi_pool_fused, dim3(2048), dim3(256), args, 0, stream);
        if (e != hipSuccess) {                      // fallback: verified R10 path
            build_tables<<<2048, 256, 0, stream>>>(fm, s4x, s4y, s4xy);
            roi_pool_q  <<<7168, 256, 0, stream>>>(fm, rois, s4x, s4y, s4xy, out, R);
        }
    } else {
        const int qblocks = B * (R * PH * PW / 4);
        roi_pool_direct<<<qblocks, 256, 0, stream>>>(fm, rois, out, R);
    }
}

// Round 12
// 24.262 us; speedup vs baseline: 19.3127x; 19.3127x over previous
//
#include <hip/hip_runtime.h>
#include <float.h>

// ROI max-pool via sliding-4-max pyramid, fused single-dispatch version.
//   S4x[y][x]  = max fm[y][x..x+3]   (indices clamped at edge)
//   S4y[y][x]  = max fm[y..y+3][x]
//   S4xy[y][x] = max fm[y..y+3][x..x+3]
// One 2048-block kernel: build phase -> lightweight 8-counter class barrier
// (replaces R11's 440us cg::grid.sync) -> query phase. blockIdx%8 pins
// (batch, y-quartile / i-group) to one XCD so table slices stay in its L2.
// Barrier: arrive = release atomicAdd on class counter; wait = relaxed
// agent-scope polls + one acquire fence. Counters zeroed per call by a
// hipMemsetAsync node. Spin timeout -> per-bin direct-from-fm path (slow
// but correct). Occupancy checked at launch; falls back to verified
// two-kernel path.
// Reference semantics:
//   h0=(int)(H*r0); h1=(int)(H*r2); step=(h1-h0)/7
//   bin i<6: [h0+i*step, h0+(i+1)*step); bin 6: [h0+6*step, h1)
//   step==0 -> all valid pixels in bin 6; empty bin -> -FLT_MAX
constexpr int H = 64, W = 64, C = 256, PH = 7, PW = 7;

typedef float f32x4 __attribute__((ext_vector_type(4)));

__device__ __forceinline__ f32x4 vmax4(f32x4 a, f32x4 b) {
    f32x4 r;
    r.x = fmaxf(a.x, b.x); r.y = fmaxf(a.y, b.y);
    r.z = fmaxf(a.z, b.z); r.w = fmaxf(a.w, b.w);
    return r;
}

// ---------- shared device bodies (verified R10/R11) ----------
__device__ __forceinline__ void build_body(
    int bx, int lane, int wave,
    const float* __restrict__ fm, float* __restrict__ s4x,
    float* __restrict__ s4y, float* __restrict__ s4xy,
    f32x4 (*lds_fm)[64], f32x4 (*lds_sx)[64])
{
    const int x8 = bx & 7;
    const int z  = bx >> 3;                          // 0..255
    const int b  = x8 >> 2;                          // batch
    const int quart = x8 & 3;                        // y-quartile (XCD match)
    const int x  = z & (W - 1);
    const int y0 = quart * 16 + ((z >> 6) << 2);     // 4-row band

    const int x1 = min(x + 1, W - 1), x2 = min(x + 2, W - 1), x3 = min(x + 3, W - 1);
    const float* fmb = fm + (size_t)b * H * W * C + (size_t)lane * 4;

    #pragma unroll
    for (int s = 0; s < 2; ++s) {
        const int slot = wave + 4 * s;
        if (slot < 7) {
            const int y = min(y0 + slot, H - 1);     // clamp == table edge rule
            const float* row = fmb + (size_t)y * W * C;
            f32x4 v0 = *(const f32x4*)(row + (size_t)x  * C);
            f32x4 v1 = *(const f32x4*)(row + (size_t)x1 * C);
            f32x4 v2 = *(const f32x4*)(row + (size_t)x2 * C);
            f32x4 v3 = *(const f32x4*)(row + (size_t)x3 * C);
            lds_fm[slot][lane] = v0;
            lds_sx[slot][lane] = vmax4(vmax4(v0, v1), vmax4(v2, v3));
        }
    }
    __syncthreads();

    const int y = y0 + wave;
    const f32x4 sx = lds_sx[wave][lane];
    const f32x4 sy = vmax4(vmax4(lds_fm[wave][lane],     lds_fm[wave + 1][lane]),
                           vmax4(lds_fm[wave + 2][lane], lds_fm[wave + 3][lane]));
    const f32x4 sxy = vmax4(vmax4(lds_sx[wave][lane],     lds_sx[wave + 1][lane]),
                            vmax4(lds_sx[wave + 2][lane], lds_sx[wave + 3][lane]));

    const size_t o = ((size_t)(b * H + y) * W + x) * C + (size_t)lane * 4;
    *(f32x4*)(s4x  + o) = sx;
    *(f32x4*)(s4y  + o) = sy;
    *(f32x4*)(s4xy + o) = sxy;
}

__device__ __forceinline__ void query_unit(
    int x8, int n, int lane, int wave,
    const float* __restrict__ fm, const float* __restrict__ rois,
    const float* __restrict__ s4x, const float* __restrict__ s4y,
    const float* __restrict__ s4xy, float* __restrict__ out, int R,
    bool use_tables)
{
    const int b = x8 >> 2;                           // batch
    const int g = x8 & 3;                            // i-group

    int i, id;
    if (g < 3) {
        i  = 2 * g + (n & 1);
        id = (n >> 1) * 4 + wave;                    // [0, 1792)
    } else {
        if (n >= 448) return;                        // pad: idle
        i  = 6;
        id = n * 4 + wave;
    }
    const int r = id / 7;                            // roi
    const int j = id - 7 * r;                        // col bin

    const float* roi = rois + ((size_t)b * R + r) * 4;
    int h0 = (int)((float)H * roi[0]);               // trunc == astype(int32)
    int w0 = (int)((float)W * roi[1]);
    int h1 = (int)((float)H * roi[2]);
    int w1 = (int)((float)W * roi[3]);
    int hs = (h1 - h0) / PH;
    int ws = (w1 - w0) / PW;

    int ys, ye, xs, xe;
    if (hs > 0) { ys = h0 + i * hs; ye = (i < PH - 1) ? (ys + hs) : h1; }
    else        { ys = h0;          ye = (i == PH - 1) ? h1 : h0; }
    if (ws > 0) { xs = w0 + j * ws; xe = (j < PW - 1) ? (xs + ws) : w1; }
    else        { xs = w0;          xe = (j == PW - 1) ? w1 : w0; }
    ys = __builtin_amdgcn_readfirstlane(max(ys, 0));
    ye = __builtin_amdgcn_readfirstlane(min(ye, H));
    xs = __builtin_amdgcn_readfirstlane(max(xs, 0));
    xe = __builtin_amdgcn_readfirstlane(min(xe, W));

    const int hl = ye - ys, wl = xe - xs;
    const f32x4 NEG = {-FLT_MAX, -FLT_MAX, -FLT_MAX, -FLT_MAX};
    f32x4 a0 = NEG, a1 = NEG, a2 = NEG, a3 = NEG;

    if (use_tables) {
        if (hl > 0 && wl > 0) {
            const bool y4 = hl >= 4, x4 = wl >= 4;   // len<=15 -> <=4 spans/dim
            const int ny = y4 ? (hl + 3) >> 2 : hl;
            const int nx = x4 ? (wl + 3) >> 2 : wl;
            const int ystep = y4 ? 4 : 1, xstep = x4 ? 4 : 1;
            const int ycl = y4 ? ye - 4 : ye - 1;
            const int xcl = x4 ? xe - 4 : xe - 1;
            const float* tb = y4 ? (x4 ? s4xy : s4y) : (x4 ? s4x : fm);
            const float* tbb = tb + (size_t)b * H * W * C + lane * 4;

            const int xo0 = min(xs,             xcl) * C;
            const int xo1 = min(xs + xstep,     xcl) * C;
            const int xo2 = min(xs + 2 * xstep, xcl) * C;
            const int xo3 = min(xs + 3 * xstep, xcl) * C;

            #pragma unroll
            for (int ky = 0; ky < 4; ++ky) {
                if (ky < ny) {                       // wave-uniform guard
                    const int y = min(ys + ystep * ky, ycl);
                    const float* rowp = tbb + (size_t)y * (W * C);
                    a0 = vmax4(a0, *(const f32x4*)(rowp + xo0));
                    if (nx > 1) a1 = vmax4(a1, *(const f32x4*)(rowp + xo1));
                    if (nx > 2) a2 = vmax4(a2, *(const f32x4*)(rowp + xo2));
                    if (nx > 3) a3 = vmax4(a3, *(const f32x4*)(rowp + xo3));
                }
            }
        }
    } else {
        // timeout path: direct from fm (always correct, no tables)
        const float* fmb2 = fm + (size_t)b * (H * W * C) + lane * 4;
        for (int y = ys; y < ye; y += 2) {
            const int yb = min(y + 1, ye - 1);
            const int ro0 = y  * (W * C);
            const int ro1 = yb * (W * C);
            for (int x = xs; x < xe; x += 2) {
                const int xb = min(x + 1, xe - 1);
                a0 = vmax4(a0, *(const f32x4*)(fmb2 + ro0 + x  * C));
                a1 = vmax4(a1, *(const f32x4*)(fmb2 + ro0 + xb * C));
                a2 = vmax4(a2, *(const f32x4*)(fmb2 + ro1 + x  * C));
                a3 = vmax4(a3, *(const f32x4*)(fmb2 + ro1 + xb * C));
            }
        }
    }
    const f32x4 acc = vmax4(vmax4(a0, a1), vmax4(a2, a3));

    size_t o = ((((size_t)b * R + r) * PH + i) * PW + j) * C + (size_t)lane * 4;
    __builtin_nontemporal_store(acc, reinterpret_cast<f32x4*>(out + o));
}

// ---------- fused kernel: grid MUST be 2048 x 256, all co-resident ----------
__global__ __launch_bounds__(256, 8) void roi_pool_fused2(
    const float* __restrict__ fm, const float* __restrict__ rois,
    float* __restrict__ s4x, float* __restrict__ s4y, float* __restrict__ s4xy,
    float* __restrict__ out, int R, unsigned* __restrict__ cnt)
{
    __shared__ f32x4 lds_fm[7][64];
    __shared__ f32x4 lds_sx[7][64];
    __shared__ int s_ok;

    const int lane = threadIdx.x & 63;
    const int wave = __builtin_amdgcn_readfirstlane(threadIdx.x >> 6);

    build_body(blockIdx.x, lane, wave, fm, s4x, s4y, s4xy, lds_fm, lds_sx);

    // ---- class barrier: 8 counters, 256 arrivals each ----
    __threadfence();                                 // release table stores
    const int cls = blockIdx.x & 7;
    const int b   = cls >> 2;
    if (threadIdx.x == 0) {
        __hip_atomic_fetch_add(&cnt[cls * 32], 1u,
                               __ATOMIC_RELEASE, __HIP_MEMORY_SCOPE_AGENT);
        int ok = 1;
        #pragma unroll
        for (int c = 0; c < 4; ++c) {                // wait batch b's 4 classes
            const unsigned* p = &cnt[(b * 4 + c) * 32];
            int spins = 0;
            while (__hip_atomic_load(p, __ATOMIC_RELAXED,
                                     __HIP_MEMORY_SCOPE_AGENT) < 256u) {
                __builtin_amdgcn_s_sleep(2);
                if (++spins > (1 << 18)) { ok = 0; break; }
            }
            if (!ok) break;
        }
        s_ok = ok;
    }
    __syncthreads();
    __threadfence();                                 // acquire table stores
    const bool use_tables = (s_ok != 0);

    // query: 7168 units folded onto 2048 blocks, preserving blockIdx%8 class
    const int base = blockIdx.x >> 3;                // 0..255
    #pragma unroll
    for (int k = 0; k < 4; ++k) {
        const int n = base + 256 * k;
        if (n < 896)
            query_unit(cls, n, lane, wave, fm, rois, s4x, s4y, s4xy, out, R,
                       use_tables);
    }
}

// ---------- verified two-kernel fallback (R10) ----------
__global__ __launch_bounds__(256) void build_tables(
    const float* __restrict__ fm, float* __restrict__ s4x,
    float* __restrict__ s4y, float* __restrict__ s4xy)
{
    __shared__ f32x4 lds_fm[7][64];
    __shared__ f32x4 lds_sx[7][64];
    const int lane = threadIdx.x & 63;
    const int wave = __builtin_amdgcn_readfirstlane(threadIdx.x >> 6);
    build_body(blockIdx.x, lane, wave, fm, s4x, s4y, s4xy, lds_fm, lds_sx);
}

__global__ __launch_bounds__(256) void roi_pool_q(
    const float* __restrict__ fm, const float* __restrict__ rois,
    const float* __restrict__ s4x, const float* __restrict__ s4y,
    const float* __restrict__ s4xy, float* __restrict__ out, int R)
{
    const int lane = threadIdx.x & 63;
    const int wave = __builtin_amdgcn_readfirstlane(threadIdx.x >> 6);
    query_unit(blockIdx.x & 7, blockIdx.x >> 3, lane, wave,
               fm, rois, s4x, s4y, s4xy, out, R, true);
}

// ---- verified direct fallback (R5 kernel) if ws too small ----
__global__ __launch_bounds__(256) void roi_pool_direct(
    const float* __restrict__ fm, const float* __restrict__ rois,
    float* __restrict__ out, int R)
{
    const int lane = threadIdx.x & 63;
    const int wave = __builtin_amdgcn_readfirstlane(threadIdx.x >> 6);
    const int b = blockIdx.x & 1;
    int m = (blockIdx.x >> 1) * 4 + wave;
    int j = m % PW; m /= PW;
    int i = m % PH; m /= PH;
    int r = m;

    const float* roi = rois + ((size_t)b * R + r) * 4;
    int h0 = (int)((float)H * roi[0]);
    int w0 = (int)((float)W * roi[1]);
    int h1 = (int)((float)H * roi[2]);
    int w1 = (int)((float)W * roi[3]);
    int hs = (h1 - h0) / PH;
    int ws = (w1 - w0) / PW;

    int ys, ye, xs, xe;
    if (hs > 0) { ys = h0 + i * hs; ye = (i < PH - 1) ? (ys + hs) : h1; }
    else        { ys = h0;          ye = (i == PH - 1) ? h1 : h0; }
    if (ws > 0) { xs = w0 + j * ws; xe = (j < PW - 1) ? (xs + ws) : w1; }
    else        { xs = w0;          xe = (j == PW - 1) ? w1 : w0; }
    ys = __builtin_amdgcn_readfirstlane(max(ys, 0));
    ye = __builtin_amdgcn_readfirstlane(min(ye, H));
    xs = __builtin_amdgcn_readfirstlane(max(xs, 0));
    xe = __builtin_amdgcn_readfirstlane(min(xe, W));

    const f32x4 NEG = {-FLT_MAX, -FLT_MAX, -FLT_MAX, -FLT_MAX};
    f32x4 a0 = NEG, a1 = NEG, a2 = NEG, a3 = NEG;
    const float* fmb = fm + (size_t)b * (H * W * C);
    const int lo = lane * 4;

    for (int y = ys; y < ye; y += 2) {
        const int y1 = min(y + 1, ye - 1);
        const int ro0 = y  * (W * C);
        const int ro1 = y1 * (W * C);
        for (int x = xs; x < xe; x += 2) {
            const int x1 = min(x + 1, xe - 1);
            a0 = vmax4(a0, *(const f32x4*)(fmb + ro0 + x  * C + lo));
            a1 = vmax4(a1, *(const f32x4*)(fmb + ro0 + x1 * C + lo));
            a2 = vmax4(a2, *(const f32x4*)(fmb + ro1 + x  * C + lo));
            a3 = vmax4(a3, *(const f32x4*)(fmb + ro1 + x1 * C + lo));
        }
    }
    f32x4 acc = vmax4(vmax4(a0, a1), vmax4(a2, a3));
    size_t o = ((((size_t)b * R + r) * PH + i) * PW + j) * C + (size_t)lo;
    __builtin_nontemporal_store(acc, reinterpret_cast<f32x4*>(out + o));
}

extern "C" void kernel_launch(void* const* d_in, const int* in_sizes, int n_in,
                              void* d_out, int out_size, void* d_ws, size_t ws_size,
                              hipStream_t stream) {
    const float* fm   = (const float*)d_in[0];
    const float* rois = (const float*)d_in[1];
    float* out = (float*)d_out;

    const int B = in_sizes[0] / (H * W * C);        // = 2
    const int R = in_sizes[1] / (B * 4);            // = 256

    const size_t tbl = (size_t)B * H * W * C;       // floats per table
    const size_t need = 3 * tbl * sizeof(float);    // 24 MB for B=2

    if (B == 2 && R == 256 && ws_size >= need + 4096) {
        float* s4x  = (float*)d_ws;
        float* s4y  = s4x + tbl;
        float* s4xy = s4y + tbl;
        unsigned* cnt = (unsigned*)((char*)d_ws + need);  // 8 counters, 128B apart

        int nb = 0;
        hipError_t oe = hipOccupancyMaxActiveBlocksPerMultiprocessor(
            &nb, roi_pool_fused2, 256, 0);

        if (oe == hipSuccess && nb >= 8) {
            hipMemsetAsync(cnt, 0, 8 * 32 * sizeof(unsigned), stream);
            roi_pool_fused2<<<2048, 256, 0, stream>>>(
                fm, rois, s4x, s4y, s4xy, out, R, cnt);
        } else {                                    // verified R10 path
            build_tables<<<2048, 256, 0, stream>>>(fm, s4x, s4y, s4xy);
            roi_pool_q  <<<7168, 256, 0, stream>>>(fm, rois, s4x, s4y, s4xy, out, R);
        }
    } else {
        const int qblocks = B * (R * PH * PW / 4);
        roi_pool_direct<<<qblocks, 256, 0, stream>>>(fm, rois, out, R);
    }
}